// Round 6
// baseline (631.081 us; speedup 1.0000x reference)
//
#include <hip/hip_runtime.h>
#include <hip/hip_bf16.h>

#define TS    2048
#define TT    4096    // B*S
#define TCHUNK 512

typedef __bf16 bf16;
typedef __bf16 bf16x8 __attribute__((ext_vector_type(8)));
typedef __bf16 bf16x4 __attribute__((ext_vector_type(4)));
typedef float  f32x4  __attribute__((ext_vector_type(4)));

#define QPL ((size_t)TT*1024)
#define KPL ((size_t)TT*256)
#define VPL ((size_t)8*64*TS)
#define APL ((size_t)TT*1024)
#define H1PL ((size_t)TT*1024)

__device__ __forceinline__ f32x4 mfma16(bf16x8 a, bf16x8 b, f32x4 c){
  return __builtin_amdgcn_mfma_f32_16x16x32_bf16(a, b, c, 0, 0, 0);
}
__device__ __forceinline__ void gload_lds16(const void* g, void* lds){
  __builtin_amdgcn_global_load_lds(
      (const __attribute__((address_space(1))) unsigned int*)g,
      (__attribute__((address_space(3))) unsigned int*)lds, 16, 0, 0);
}
__device__ __forceinline__ void split3f(float x, bf16& h, bf16& m, bf16& l){
  h = (bf16)x; float r = x - (float)h;
  m = (bf16)r; r -= (float)m;
  l = (bf16)r;
}

// ---------------- transpose + f32->bf16 (1-way, MoE weights) ----------------
__global__ __launch_bounds__(256) void tcvt_k(const float* __restrict__ src, bf16* __restrict__ dst,
                                              int R, int C, long srcMatStride, long dstMatStride, long dstOff){
  __shared__ float tile[32][33];
  int z = blockIdx.z;
  const float* s = src + (size_t)z*srcMatStride;
  bf16* d = dst + (size_t)z*dstMatStride + dstOff;
  int r0 = blockIdx.y*32, c0 = blockIdx.x*32;
  int tx = threadIdx.x, ty = threadIdx.y;
  #pragma unroll
  for (int i=0;i<4;i++)
    tile[ty+i*8][tx] = s[(size_t)(r0+ty+i*8)*C + c0+tx];
  __syncthreads();
  #pragma unroll
  for (int i=0;i<4;i++)
    d[(size_t)(c0+ty+i*8)*R + r0+tx] = (bf16)tile[tx][ty+i*8];
}

// ---------------- transpose + 3-way split (precise weights) ----------------
// src [R][C] f32 -> 3 planes of [C][R] bf16 at dst + p*planeStride (+dstOff)
__global__ __launch_bounds__(256) void tcvt3_k(const float* __restrict__ src, bf16* __restrict__ dst,
                                               int R, int C, long planeStride, long dstOff){
  __shared__ float tile[32][33];
  int r0 = blockIdx.y*32, c0 = blockIdx.x*32;
  int tx = threadIdx.x, ty = threadIdx.y;
  #pragma unroll
  for (int i=0;i<4;i++)
    tile[ty+i*8][tx] = src[(size_t)(r0+ty+i*8)*C + c0+tx];
  __syncthreads();
  #pragma unroll
  for (int i=0;i<4;i++){
    float v = tile[tx][ty+i*8];
    bf16 h,m,l; split3f(v,h,m,l);
    size_t o = dstOff + (size_t)(c0+ty+i*8)*R + r0+tx;
    dst[o] = h; dst[planeStride + o] = m; dst[2*planeStride + o] = l;
  }
}

// ---------------- RMSNorm f32 -> bf16 (1-way, for MoE h2) ----------------
__global__ __launch_bounds__(256) void rmsnorm_k(const float* __restrict__ x, const float* __restrict__ g,
                                                 bf16* __restrict__ o){
  int row = blockIdx.x, tid = threadIdx.x, wid = tid>>6, lane = tid&63;
  f32x4 v = ((const f32x4*)(x + (size_t)row*1024))[tid];
  float ss = v[0]*v[0]+v[1]*v[1]+v[2]*v[2]+v[3]*v[3];
  #pragma unroll
  for (int m=1;m<64;m<<=1) ss += __shfl_xor(ss, m);
  __shared__ float red[4];
  if (lane==0) red[wid] = ss;
  __syncthreads();
  float tot = red[0]+red[1]+red[2]+red[3];
  float inv = rsqrtf(tot*(1.f/1024.f) + 1e-6f);
  f32x4 gv = ((const f32x4*)g)[tid];
  bf16x4 ov;
  #pragma unroll
  for (int i=0;i<4;i++) ov[i] = (bf16)(v[i]*inv*gv[i]);
  *(bf16x4*)(o + (size_t)row*1024 + tid*4) = ov;
}

// ---------------- RMSNorm f32 -> 3-way split bf16 planes ----------------
__global__ __launch_bounds__(256) void rmsnorm3_k(const float* __restrict__ x, const float* __restrict__ g,
                                                  bf16* __restrict__ o3){
  int row = blockIdx.x, tid = threadIdx.x, wid = tid>>6, lane = tid&63;
  f32x4 v = ((const f32x4*)(x + (size_t)row*1024))[tid];
  float ss = v[0]*v[0]+v[1]*v[1]+v[2]*v[2]+v[3]*v[3];
  #pragma unroll
  for (int m=1;m<64;m<<=1) ss += __shfl_xor(ss, m);
  __shared__ float red[4];
  if (lane==0) red[wid] = ss;
  __syncthreads();
  float tot = red[0]+red[1]+red[2]+red[3];
  float inv = rsqrtf(tot*(1.f/1024.f) + 1e-6f);
  f32x4 gv = ((const f32x4*)g)[tid];
  #pragma unroll
  for (int i=0;i<4;i++){
    float val = v[i]*inv*gv[i];
    bf16 h,m,l; split3f(val,h,m,l);
    size_t idx = (size_t)row*1024 + tid*4 + i;
    o3[idx] = h; o3[H1PL + idx] = m; o3[2*H1PL + idx] = l;
  }
}

// ---------------- plain bf16 GEMM (MoE path) ----------------
template<int OUT_BF16, int RESID, int GATHER, int GROUPED>
__global__ __launch_bounds__(256) void gemm_k(
    const bf16* __restrict__ Aptr, int lda,
    const bf16* __restrict__ Bt, long bMatStride,
    void* __restrict__ Cout, int ldc,
    const float* __restrict__ resid,
    const int* __restrict__ gidx,
    const int* __restrict__ grpBase,
    const int* __restrict__ grpCnt,
    int M, int K){
  int tid = threadIdx.x;
  int wid = tid >> 6, lane = tid & 63;
  int lr = lane & 15, lg = lane >> 4;
  int e = blockIdx.z;
  int base = GROUPED ? grpBase[e] : 0;
  int cnt  = GROUPED ? grpCnt[e]  : M;
  int m0 = blockIdx.y * 128;
  if (m0 >= cnt) return;
  int bn0 = blockIdx.x * 128;
  const bf16* Bte = Bt + (size_t)e * bMatStride;

  __shared__ __align__(16) bf16 As[128*32];
  __shared__ __align__(16) bf16 Bs[128*32];

  int rA0 = tid >> 2, colA = (tid & 3) * 8;
  long arow[2], brow[2];
  #pragma unroll
  for (int i=0;i<2;i++){
    int r = rA0 + i*64;
    int ar = m0 + r; if (ar > cnt-1) ar = cnt-1;
    arow[i] = GATHER ? (long)gidx[base + ar] : (long)(base + ar);
    brow[i] = bn0 + r;
  }

  f32x4 zero4 = {0.f,0.f,0.f,0.f};
  f32x4 acc[4][4];
  #pragma unroll
  for (int m=0;m<4;m++)
    #pragma unroll
    for (int n=0;n<4;n++) acc[m][n] = zero4;

  char* ldsA = (char*)As + wid*1024;
  char* ldsB = (char*)Bs + wid*1024;
  int wr = (wid>>1)*64, wc = (wid&1)*64;

  for (int k0 = 0; k0 < K; k0 += 32){
    #pragma unroll
    for (int i=0;i<2;i++){
      gload_lds16(Aptr + arow[i]*lda + k0 + colA, ldsA + i*4096);
      gload_lds16(Bte  + brow[i]*K   + k0 + colA, ldsB + i*4096);
    }
    asm volatile("s_waitcnt vmcnt(0)" ::: "memory");
    __syncthreads();
    bf16x8 af[4], bfr[4];
    #pragma unroll
    for (int m=0;m<4;m++) af[m]  = *(const bf16x8*)&As[(wr + m*16 + lr)*32 + lg*8];
    #pragma unroll
    for (int n=0;n<4;n++) bfr[n] = *(const bf16x8*)&Bs[(wc + n*16 + lr)*32 + lg*8];
    #pragma unroll
    for (int m=0;m<4;m++)
      #pragma unroll
      for (int n=0;n<4;n++)
        acc[m][n] = mfma16(af[m], bfr[n], acc[m][n]);
    __syncthreads();
  }
  #pragma unroll
  for (int m=0;m<4;m++){
    #pragma unroll
    for (int j=0;j<4;j++){
      int gr = m0 + wr + m*16 + lg*4 + j;
      if (gr < cnt){
        size_t orow = (size_t)(base + gr);
        #pragma unroll
        for (int n=0;n<4;n++){
          int gc = bn0 + wc + n*16 + lr;
          float v = acc[m][n][j];
          if (OUT_BF16){
            ((bf16*)Cout)[orow*ldc + gc] = (bf16)v;
          } else {
            float rv = RESID ? resid[orow*ldc + gc] : 0.f;
            ((float*)Cout)[orow*ldc + gc] = v + rv;
          }
        }
      }
    }
  }
}

// ---------------- split-3 precise GEMM: C f32 = A3 * B3^T (+resid) ----------------
// A3: 3 planes [M][K] bf16 (stride aPL); B3: 3 planes [N][K] bf16 (stride bPL)
template<int RESID>
__global__ __launch_bounds__(256) void gemm3_k(
    const bf16* __restrict__ A3, long aPL, int lda,
    const bf16* __restrict__ B3, long bPL, int K,
    float* __restrict__ C, int ldc,
    const float* __restrict__ resid){
  int tid = threadIdx.x;
  int wid = tid >> 6, lane = tid & 63;
  int lr = lane & 15, lg = lane >> 4;
  int m0 = blockIdx.y * 128, bn0 = blockIdx.x * 128;

  __shared__ __align__(16) bf16 As[3*128*32];
  __shared__ __align__(16) bf16 Bs[3*128*32];

  int rA0 = tid >> 2, colA = (tid & 3) * 8;
  f32x4 zero4 = {0.f,0.f,0.f,0.f};
  f32x4 acc[4][4];
  #pragma unroll
  for (int m=0;m<4;m++)
    #pragma unroll
    for (int n=0;n<4;n++) acc[m][n] = zero4;

  int wr = (wid>>1)*64, wc = (wid&1)*64;

  for (int k0 = 0; k0 < K; k0 += 32){
    #pragma unroll
    for (int p=0;p<3;p++){
      #pragma unroll
      for (int i=0;i<2;i++){
        int r = rA0 + i*64;
        gload_lds16(A3 + (size_t)p*aPL + (size_t)(m0 + r)*lda + k0 + colA,
                    (char*)As + p*8192 + wid*1024 + i*4096);
        gload_lds16(B3 + (size_t)p*bPL + (size_t)(bn0 + r)*K + k0 + colA,
                    (char*)Bs + p*8192 + wid*1024 + i*4096);
      }
    }
    asm volatile("s_waitcnt vmcnt(0)" ::: "memory");
    __syncthreads();
    bf16x8 af[3][4], bfr[3][4];
    #pragma unroll
    for (int p=0;p<3;p++){
      #pragma unroll
      for (int m=0;m<4;m++) af[p][m]  = *(const bf16x8*)&As[p*4096 + (wr + m*16 + lr)*32 + lg*8];
      #pragma unroll
      for (int n=0;n<4;n++) bfr[p][n] = *(const bf16x8*)&Bs[p*4096 + (wc + n*16 + lr)*32 + lg*8];
    }
    #pragma unroll
    for (int m=0;m<4;m++)
      #pragma unroll
      for (int n=0;n<4;n++){
        f32x4 a = acc[m][n];
        a = mfma16(af[0][m], bfr[0][n], a);   // hh
        a = mfma16(af[0][m], bfr[1][n], a);   // hm
        a = mfma16(af[1][m], bfr[0][n], a);   // mh
        a = mfma16(af[0][m], bfr[2][n], a);   // hl
        a = mfma16(af[1][m], bfr[1][n], a);   // mm
        a = mfma16(af[2][m], bfr[0][n], a);   // lh
        acc[m][n] = a;
      }
    __syncthreads();
  }
  #pragma unroll
  for (int m=0;m<4;m++){
    #pragma unroll
    for (int j=0;j<4;j++){
      size_t orow = (size_t)(m0 + wr + m*16 + lg*4 + j);
      #pragma unroll
      for (int n=0;n<4;n++){
        int gc = bn0 + wc + n*16 + lr;
        float v = acc[m][n][j];
        if (RESID) v += resid[orow*ldc + gc];
        C[orow*ldc + gc] = v;
      }
    }
  }
}

// ---------------- per-head QK RMSNorm + RoPE (f32) -> 3-way split q/k ----------------
__global__ __launch_bounds__(256) void rope3_k(const float* __restrict__ qkv, bf16* __restrict__ Q3,
                                               bf16* __restrict__ K3, const int* __restrict__ idxp,
                                               const float* __restrict__ qg, const float* __restrict__ kg){
  int tid = threadIdx.x, wid = tid>>6, lane = tid&63;
  int u = blockIdx.x*4 + wid;   // 0 .. TT*20-1
  int t = u / 20, r = u % 20;
  bool isq = (r < 16);
  int srcOff = isq ? r*64 : 1024 + (r-16)*64;
  float val = qkv[(size_t)t*1536 + srcOff + lane];
  float ss = val*val;
  #pragma unroll
  for (int m=1;m<64;m<<=1) ss += __shfl_xor(ss, m);
  float inv = rsqrtf(ss*(1.f/64.f) + 1e-6f);
  const float* gm = isq ? qg : kg;
  val = val * inv * gm[lane];
  bool rope = ((idxp[0] + 1) % 4) != 0;
  if (rope){
    int s = t & (TS-1);
    float fi = (float)(lane & ~1);
    float theta = (float)exp((double)fi * -0.14391156831212787); // f64 -> correctly-rounded f32
    float ang = (float)s * theta;
    float sn, cs;
    sincosf(ang, &sn, &cs);
    float other = __shfl_xor(val, 1);
    val = (lane & 1) ? (other*sn + val*cs) : (val*cs - other*sn);
  }
  bf16 h,m2,l; split3f(val,h,m2,l);
  if (isq){
    size_t base = (size_t)t*1024 + r*64 + lane;
    Q3[base] = h; Q3[QPL + base] = m2; Q3[2*QPL + base] = l;
  } else {
    size_t base = (size_t)t*256 + (r-16)*64 + lane;
    K3[base] = h; K3[KPL + base] = m2; K3[2*KPL + base] = l;
  }
}

// ---------------- V transpose f32 -> 3-way split bf16 [b4+kvh][64][S] ----------------
__global__ __launch_bounds__(256) void vtrans3_k(const float* __restrict__ src, bf16* __restrict__ dst){
  __shared__ float tile[32][33];
  int z = blockIdx.z;  // b*4 + kvh
  const float* s = src + (size_t)(z>>2)*((size_t)TS*1536) + (z&3)*64 + 1280;
  int r0 = blockIdx.y*32, c0 = blockIdx.x*32;
  int tx = threadIdx.x, ty = threadIdx.y;
  #pragma unroll
  for (int i=0;i<4;i++)
    tile[ty+i*8][tx] = s[(size_t)(r0+ty+i*8)*1536 + c0+tx];
  __syncthreads();
  size_t zb = (size_t)z*(64*TS);
  #pragma unroll
  for (int i=0;i<4;i++){
    float v = tile[tx][ty+i*8];
    bf16 h,m,l; split3f(v,h,m,l);
    size_t o = zb + (size_t)(c0+ty+i*8)*TS + r0+tx;
    dst[o] = h; dst[VPL + o] = m; dst[2*VPL + o] = l;
  }
}

// ---------------- precise chunked-causal GQA flash attention (split MFMA) ----------------
// Q3:[3][T][16][64] K3:[3][T][4][64] V3:[3][b4+kvh][64][S]  out: 3-way split [3][T][1024]
__global__ __launch_bounds__(256) void attn3_k(const bf16* __restrict__ Q3, const bf16* __restrict__ K3,
                                               const bf16* __restrict__ V3, bf16* __restrict__ A3,
                                               const int* __restrict__ idxp){
  int tid = threadIdx.x, wid = tid>>6, lane = tid&63;
  int lr = lane&15, lg = lane>>4;
  int qt = blockIdx.x, h = blockIdx.y, b = blockIdx.z;
  int kvh = h >> 2;
  int q0 = qt*64;
  bool rope = ((idxp[0]+1) % 4) != 0;
  int kstart = rope ? (q0 / TCHUNK) * TCHUNK : 0;
  int ntiles = (q0 + 64 - kstart) >> 6;

  __shared__ __align__(16) bf16 Ks[3*64*64];
  __shared__ __align__(16) bf16 Vs[3*64*64];
  __shared__ __align__(16) bf16 Ps[2][4][16*64];

  // Q fragments straight to registers (per-wave rows)
  bf16x8 qf[3][2];
  {
    size_t qrow = (size_t)(b*TS + q0 + wid*16 + lr);
    #pragma unroll
    for (int p=0;p<3;p++)
      #pragma unroll
      for (int kf=0;kf<2;kf++)
        qf[p][kf] = *(const bf16x8*)&Q3[(size_t)p*QPL + qrow*1024 + h*64 + kf*32 + lg*8];
  }

  f32x4 o[4];
  f32x4 zero4 = {0.f,0.f,0.f,0.f};
  #pragma unroll
  for (int n=0;n<4;n++) o[n] = zero4;
  float mrow[4], lrow[4];
  #pragma unroll
  for (int j=0;j<4;j++){ mrow[j] = -1e30f; lrow[j] = 0.f; }

  for (int kt=0; kt<ntiles; kt++){
    int kt0 = kstart + kt*64;
    {
      int rr = tid>>3, cc = (tid&7)*8;
      #pragma unroll
      for (int p=0;p<3;p++){
        #pragma unroll
        for (int i=0;i<2;i++){
          int r = rr + i*32;
          gload_lds16(K3 + (size_t)p*KPL + ((size_t)(b*TS + kt0 + r))*256 + kvh*64 + cc,
                      (char*)Ks + p*8192 + wid*1024 + i*4096);
          gload_lds16(V3 + (size_t)p*VPL + ((size_t)((b*4 + kvh)*64 + r))*TS + kt0 + cc,
                      (char*)Vs + p*8192 + wid*1024 + i*4096);
        }
      }
      asm volatile("s_waitcnt vmcnt(0)" ::: "memory");
      __syncthreads();
    }
    // QK^T: 3-way x 3-way, 6 products per fragment pair
    f32x4 sc[4];
    #pragma unroll
    for (int cf=0; cf<4; cf++){
      bf16x8 kh0 = *(const bf16x8*)&Ks[0*4096 + (cf*16+lr)*64 + lg*8];
      bf16x8 kh1 = *(const bf16x8*)&Ks[0*4096 + (cf*16+lr)*64 + 32 + lg*8];
      bf16x8 km0 = *(const bf16x8*)&Ks[1*4096 + (cf*16+lr)*64 + lg*8];
      bf16x8 km1 = *(const bf16x8*)&Ks[1*4096 + (cf*16+lr)*64 + 32 + lg*8];
      bf16x8 kl0 = *(const bf16x8*)&Ks[2*4096 + (cf*16+lr)*64 + lg*8];
      bf16x8 kl1 = *(const bf16x8*)&Ks[2*4096 + (cf*16+lr)*64 + 32 + lg*8];
      f32x4 a = zero4;
      a = mfma16(qf[0][0], kh0, a); a = mfma16(qf[0][1], kh1, a);  // hh
      a = mfma16(qf[0][0], km0, a); a = mfma16(qf[0][1], km1, a);  // hm
      a = mfma16(qf[1][0], kh0, a); a = mfma16(qf[1][1], kh1, a);  // mh
      a = mfma16(qf[0][0], kl0, a); a = mfma16(qf[0][1], kl1, a);  // hl
      a = mfma16(qf[1][0], km0, a); a = mfma16(qf[1][1], km1, a);  // mm
      a = mfma16(qf[2][0], kh0, a); a = mfma16(qf[2][1], kh1, a);  // lh
      sc[cf] = a;
    }
    // online softmax (f32), write P split 2-way
    #pragma unroll
    for (int j=0;j<4;j++){
      int qtok = q0 + wid*16 + lg*4 + j;
      float pmax = -1e30f;
      #pragma unroll
      for (int cf=0;cf<4;cf++){
        int ktok = kt0 + cf*16 + lr;
        float sv = (ktok <= qtok) ? sc[cf][j]*0.125f : -1e30f;
        sc[cf][j] = sv;
        pmax = fmaxf(pmax, sv);
      }
      #pragma unroll
      for (int m=1;m<16;m<<=1) pmax = fmaxf(pmax, __shfl_xor(pmax, m));
      float mnew = fmaxf(mrow[j], pmax);
      float corr = __expf(mrow[j]-mnew);
      float psum = 0.f;
      #pragma unroll
      for (int cf=0;cf<4;cf++){
        float p = __expf(sc[cf][j]-mnew);
        sc[cf][j] = p;
        psum += p;
      }
      #pragma unroll
      for (int m=1;m<16;m<<=1) psum += __shfl_xor(psum, m);
      lrow[j] = lrow[j]*corr + psum;
      mrow[j] = mnew;
      #pragma unroll
      for (int n=0;n<4;n++) o[n][j] *= corr;
      #pragma unroll
      for (int cf=0;cf<4;cf++){
        float p = sc[cf][j];
        bf16 ph = (bf16)p;
        bf16 pl = (bf16)(p - (float)ph);
        int pidx = (lg*4+j)*64 + cf*16 + lr;
        Ps[0][wid][pidx] = ph;
        Ps[1][wid][pidx] = pl;
      }
    }
    // PV: P 2-way x V 3-way, 5 products per fragment pair
    bf16x8 pa[2][2];
    #pragma unroll
    for (int p=0;p<2;p++){
      pa[p][0] = *(const bf16x8*)&Ps[p][wid][lr*64 + lg*8];
      pa[p][1] = *(const bf16x8*)&Ps[p][wid][lr*64 + 32 + lg*8];
    }
    #pragma unroll
    for (int n=0;n<4;n++){
      bf16x8 vf[3][2];
      #pragma unroll
      for (int p=0;p<3;p++){
        vf[p][0] = *(const bf16x8*)&Vs[p*4096 + (n*16+lr)*64 + lg*8];
        vf[p][1] = *(const bf16x8*)&Vs[p*4096 + (n*16+lr)*64 + 32 + lg*8];
      }
      f32x4 a = o[n];
      a = mfma16(pa[0][0], vf[0][0], a); a = mfma16(pa[0][1], vf[0][1], a);  // hh
      a = mfma16(pa[0][0], vf[1][0], a); a = mfma16(pa[0][1], vf[1][1], a);  // hm
      a = mfma16(pa[1][0], vf[0][0], a); a = mfma16(pa[1][1], vf[0][1], a);  // lh
      a = mfma16(pa[0][0], vf[2][0], a); a = mfma16(pa[0][1], vf[2][1], a);  // hl
      a = mfma16(pa[1][0], vf[1][0], a); a = mfma16(pa[1][1], vf[1][1], a);  // lm
      o[n] = a;
    }
    __syncthreads();
  }
  // epilogue: normalize + 3-way split store for the precise w_o GEMM
  #pragma unroll
  for (int j=0;j<4;j++){
    int qtok = q0 + wid*16 + lg*4 + j;
    float invl = 1.f / lrow[j];
    size_t rowb = ((size_t)(b*TS + qtok))*1024 + h*64;
    #pragma unroll
    for (int n=0;n<4;n++){
      float v = o[n][j]*invl;
      bf16 h2,m2,l2; split3f(v,h2,m2,l2);
      size_t oidx = rowb + n*16 + lr;
      A3[oidx] = h2; A3[APL + oidx] = m2; A3[2*APL + oidx] = l2;
    }
  }
}

// ---------------- fused f32 router ----------------
__global__ __launch_bounds__(256) void router_k(const float* __restrict__ x2, const float* __restrict__ g2,
                                                const float* __restrict__ wr,
                                                int* __restrict__ topi, float* __restrict__ topw){
  int tid = threadIdx.x, wid = tid>>6, lane = tid&63;
  int t = blockIdx.x*4 + wid;
  const float* row = x2 + (size_t)t*1024;
  f32x4 xv[4];
  float ss = 0.f;
  #pragma unroll
  for (int j=0;j<4;j++){
    xv[j] = ((const f32x4*)row)[lane + j*64];
    ss += xv[j][0]*xv[j][0]+xv[j][1]*xv[j][1]+xv[j][2]*xv[j][2]+xv[j][3]*xv[j][3];
  }
  #pragma unroll
  for (int m=1;m<64;m<<=1) ss += __shfl_xor(ss, m);
  float inv = 1.f / sqrtf(ss*(1.f/1024.f) + 1e-6f);
  float a[8] = {0,0,0,0,0,0,0,0};
  #pragma unroll
  for (int j=0;j<4;j++){
    #pragma unroll
    for (int c=0;c<4;c++){
      int d = (lane + j*64)*4 + c;
      float hv = xv[j][c]*inv*g2[d];
      f32x4 wa = ((const f32x4*)(wr + (size_t)d*8))[0];
      f32x4 wb = ((const f32x4*)(wr + (size_t)d*8))[1];
      a[0]+=hv*wa[0]; a[1]+=hv*wa[1]; a[2]+=hv*wa[2]; a[3]+=hv*wa[3];
      a[4]+=hv*wb[0]; a[5]+=hv*wb[1]; a[6]+=hv*wb[2]; a[7]+=hv*wb[3];
    }
  }
  #pragma unroll
  for (int e2=0;e2<8;e2++)
    #pragma unroll
    for (int m=1;m<64;m<<=1) a[e2] += __shfl_xor(a[e2], m);
  if (lane==0){
    int i0=0; float l0=a[0];
    #pragma unroll
    for (int e2=1;e2<8;e2++) if (a[e2] > l0){ l0=a[e2]; i0=e2; }
    int i1=-1; float l1=-1e30f;
    #pragma unroll
    for (int e2=0;e2<8;e2++){ if (e2==i0) continue; if (a[e2] > l1){ l1=a[e2]; i1=e2; } }
    float w0 = 1.f/(1.f + __expf(l1 - l0));
    topi[t*2]=i0; topi[t*2+1]=i1;
    topw[t*2]=w0; topw[t*2+1]=1.f-w0;
  }
}

__global__ void count_k(const int* __restrict__ topi, int* __restrict__ cnt){
  int i = blockIdx.x*256 + threadIdx.x;
  if (i < TT*2) atomicAdd(&cnt[topi[i]], 1);
}
__global__ void scan_k(const int* __restrict__ cnt, int* __restrict__ basep){
  if (threadIdx.x==0){ int run=0; for (int e=0;e<8;e++){ basep[e]=run; run+=cnt[e]; } }
}
__global__ void scatter_k(const int* __restrict__ topi, const int* __restrict__ basep,
                          int* __restrict__ cursor, int* __restrict__ rowsb, int* __restrict__ t2p){
  int i = blockIdx.x*256 + threadIdx.x;
  if (i < TT*2){
    int e = topi[i];
    int p = basep[e] + atomicAdd(&cursor[e], 1);
    rowsb[p] = i>>1;
    t2p[i] = p;
  }
}

__global__ void silumul_k(const bf16* __restrict__ raw, bf16* __restrict__ o, int rows){
  int i = blockIdx.x*256 + threadIdx.x;
  int pos = i >> 7, f = (i & 127)*8;
  if (pos >= rows) return;
  bf16x8 g = *(const bf16x8*)&raw[(size_t)pos*2048 + f];
  bf16x8 u = *(const bf16x8*)&raw[(size_t)pos*2048 + 1024 + f];
  bf16x8 r;
  #pragma unroll
  for (int k=0;k<8;k++){
    float gf = (float)g[k], uf = (float)u[k];
    r[k] = (bf16)(gf * uf / (1.f + __expf(-gf)));
  }
  *(bf16x8*)&o[(size_t)pos*1024 + f] = r;
}

__global__ void combine_k(const float* __restrict__ acc, const bf16* __restrict__ eo,
                          const float* __restrict__ topw, const int* __restrict__ t2p,
                          float* __restrict__ out){
  int i = blockIdx.x*256 + threadIdx.x;
  int t = i >> 8, c = (i & 255)*4;
  int p0 = t2p[t*2], p1 = t2p[t*2+1];
  float w0 = topw[t*2], w1 = topw[t*2+1];
  f32x4 a = *(const f32x4*)&acc[(size_t)t*1024 + c];
  bf16x4 e0 = *(const bf16x4*)&eo[(size_t)p0*1024 + c];
  bf16x4 e1 = *(const bf16x4*)&eo[(size_t)p1*1024 + c];
  f32x4 r;
  #pragma unroll
  for (int k=0;k<4;k++) r[k] = a[k] + w0*(float)e0[k] + w1*(float)e1[k];
  *(f32x4*)&out[(size_t)t*1024 + c] = r;
}

extern "C" void kernel_launch(void* const* d_in, const int* in_sizes, int n_in,
                              void* d_out, int out_size, void* d_ws, size_t ws_size,
                              hipStream_t stream){
  const float* x        = (const float*)d_in[0];
  const int*   idx      = (const int*)d_in[1];
  const float* gamma1   = (const float*)d_in[2];
  const float* gamma2   = (const float*)d_in[3];
  const float* qg       = (const float*)d_in[4];
  const float* kg       = (const float*)d_in[5];
  const float* w_q      = (const float*)d_in[6];
  const float* w_k      = (const float*)d_in[7];
  const float* w_v      = (const float*)d_in[8];
  const float* w_o      = (const float*)d_in[9];
  const float* w_router = (const float*)d_in[10];
  const float* sh_wg    = (const float*)d_in[11];
  const float* sh_wu    = (const float*)d_in[12];
  const float* sh_wd    = (const float*)d_in[13];
  const float* e_wg     = (const float*)d_in[14];
  const float* e_wu     = (const float*)d_in[15];
  const float* e_wd     = (const float*)d_in[16];
  float* out = (float*)d_out;

  char* ws = (char*)d_ws;
  size_t off = 0;
  auto alloc = [&](size_t n)->char*{ char* p = ws + off; off += (n + 255) & ~(size_t)255; return p; };

  const long PLQKV = (long)1536*1024;   // plane stride for wqkv3
  const long PLSQ  = (long)1024*1024;

  bf16* wqkv3  = (bf16*)alloc((size_t)3*1536*1024*2);
  bf16* wo3    = (bf16*)alloc((size_t)3*1024*1024*2);
  bf16* shwgu_t= (bf16*)alloc((size_t)2048*1024*2);
  bf16* shwd_t = (bf16*)alloc((size_t)1024*1024*2);
  bf16* ewgu_t = (bf16*)alloc((size_t)8*2048*1024*2);
  bf16* ewd_t  = (bf16*)alloc((size_t)8*1024*1024*2);
  bf16* h1s    = (bf16*)alloc((size_t)3*TT*1024*2);
  float* qkvraw= (float*)alloc((size_t)TT*1536*4);     // reused as attn3 splits
  bf16* q3     = (bf16*)alloc((size_t)3*TT*1024*2);    // reused as h2 region later
  bf16* k3     = (bf16*)alloc((size_t)3*TT*256*2);
  bf16* v3     = (bf16*)alloc((size_t)3*8*64*TS*2);
  float* x2    = (float*)alloc((size_t)TT*1024*4);
  float* accb  = (float*)alloc((size_t)TT*1024*4);
  char* BUF1   = alloc((size_t)8192*2048*2);           // shraw / guraw
  char* BUF2   = alloc((size_t)8192*1024*2);           // shg / gu
  bf16* eo     = (bf16*)alloc((size_t)8192*1024*2);
  int*   topi  = (int*)alloc((size_t)TT*2*4);
  float* topw  = (float*)alloc((size_t)TT*2*4);
  int*   rowsb = (int*)alloc((size_t)TT*2*4);
  int*   t2p   = (int*)alloc((size_t)TT*2*4);
  int*   cntp  = (int*)alloc(256);
  int*   basep = (int*)alloc(256);
  int*   curp  = (int*)alloc(256);
  (void)ws_size; (void)in_sizes; (void)n_in; (void)out_size;

  bf16* a3     = (bf16*)qkvraw;        // attn output splits (qkvraw dead by then)
  bf16* h2     = q3;                   // q3 dead after attention
  bf16* shraw  = (bf16*)BUF1;
  bf16* guraw  = (bf16*)BUF1;
  bf16* shg    = (bf16*)BUF2;
  bf16* gu     = (bf16*)BUF2;

  dim3 tb(32,8);
  // precise weights: transpose + 3-way split
  tcvt3_k<<<dim3(32,32,1), tb, 0, stream>>>(w_q, wqkv3, 1024,1024, PLQKV, 0);
  tcvt3_k<<<dim3(8,32,1),  tb, 0, stream>>>(w_k, wqkv3, 1024,256,  PLQKV, (long)1024*1024);
  tcvt3_k<<<dim3(8,32,1),  tb, 0, stream>>>(w_v, wqkv3, 1024,256,  PLQKV, (long)1280*1024);
  tcvt3_k<<<dim3(32,32,1), tb, 0, stream>>>(w_o, wo3,   1024,1024, PLSQ, 0);
  // MoE weights: 1-way bf16
  tcvt_k<<<dim3(32,32,1), tb, 0, stream>>>(sh_wg, shwgu_t, 1024,1024, 0,0, 0);
  tcvt_k<<<dim3(32,32,1), tb, 0, stream>>>(sh_wu, shwgu_t, 1024,1024, 0,0, (long)1024*1024);
  tcvt_k<<<dim3(32,32,1), tb, 0, stream>>>(sh_wd, shwd_t, 1024,1024, 0,0, 0);
  tcvt_k<<<dim3(32,32,8), tb, 0, stream>>>(e_wg, ewgu_t, 1024,1024, (long)1024*1024, (long)2048*1024, 0);
  tcvt_k<<<dim3(32,32,8), tb, 0, stream>>>(e_wu, ewgu_t, 1024,1024, (long)1024*1024, (long)2048*1024, (long)1024*1024);
  tcvt_k<<<dim3(32,32,8), tb, 0, stream>>>(e_wd, ewd_t,  1024,1024, (long)1024*1024, (long)1024*1024, 0);

  // 1. h1 = rmsnorm(x, gamma1), 3-way split
  rmsnorm3_k<<<TT, 256, 0, stream>>>(x, gamma1, h1s);
  // 2. qkv (f32) = h1 @ [wq|wk|wv] via split-3 MFMA
  gemm3_k<0><<<dim3(12,32,1), 256, 0, stream>>>(h1s, (long)H1PL, 1024, wqkv3, PLQKV, 1024,
                                                qkvraw, 1536, nullptr);
  // 3. q/k rmsnorm + rope (f32) -> 3-way splits; V transpose -> 3-way splits
  rope3_k<<<TT*20/4, 256, 0, stream>>>(qkvraw, q3, k3, idx, qg, kg);
  vtrans3_k<<<dim3(2,64,8), tb, 0, stream>>>(qkvraw, v3);
  // 4. precise attention -> 3-way split output (into a3 == qkvraw space)
  attn3_k<<<dim3(32,16,2), 256, 0, stream>>>(q3, k3, v3, a3, idx);
  // 5. x2 = attn @ w_o + x (split-3 MFMA, f32 out)
  gemm3_k<1><<<dim3(8,32,1), 256, 0, stream>>>(a3, (long)APL, 1024, wo3, PLSQ, 1024,
                                               x2, 1024, x);
  // 6. h2 = rmsnorm(x2, gamma2) bf16 (MoE input)
  rmsnorm_k<<<TT, 256, 0, stream>>>(x2, gamma2, h2);
  // 7. f32 router + routing structures
  router_k<<<TT/4, 256, 0, stream>>>(x2, gamma2, w_router, topi, topw);
  hipMemsetAsync(cntp, 0, 3*256, stream);
  count_k<<<32, 256, 0, stream>>>(topi, cntp);
  scan_k<<<1, 64, 0, stream>>>(cntp, basep);
  scatter_k<<<32, 256, 0, stream>>>(topi, basep, curp, rowsb, t2p);
  // 8. shared expert (bf16)
  gemm_k<1,0,0,0><<<dim3(16,32,1), 256, 0, stream>>>(h2,1024, shwgu_t,0, shraw,2048,
                                                     nullptr, nullptr, nullptr, nullptr, TT, 1024);
  silumul_k<<<(TT*128)/256, 256, 0, stream>>>(shraw, shg, TT);
  gemm_k<0,1,0,0><<<dim3(8,32,1), 256, 0, stream>>>(shg,1024, shwd_t,0, accb,1024,
                                                    x2, nullptr, nullptr, nullptr, TT, 1024);
  // 9. routed experts (grouped, gathered; grid.y=64 covers up to 8192 rows/expert)
  gemm_k<1,0,1,1><<<dim3(16,64,8), 256, 0, stream>>>(h2,1024, ewgu_t,(long)2048*1024, guraw,2048,
                                                     nullptr, rowsb, basep, cntp, TT, 1024);
  silumul_k<<<(2*TT*128)/256, 256, 0, stream>>>(guraw, gu, 2*TT);
  gemm_k<1,0,0,1><<<dim3(8,64,8), 256, 0, stream>>>(gu,1024, ewd_t,(long)1024*1024, eo,1024,
                                                    nullptr, nullptr, basep, cntp, TT, 1024);
  // 10. combine
  combine_k<<<TT, 256, 0, stream>>>(accb, eo, topw, t2p, out);
}

// Round 7
// 621.513 us; speedup vs baseline: 1.0154x; 1.0154x over previous
//
#include <hip/hip_runtime.h>
#include <hip/hip_bf16.h>

#define TS    2048
#define TT    4096    // B*S
#define TCHUNK 512

typedef __bf16 bf16;
typedef __bf16 bf16x8 __attribute__((ext_vector_type(8)));
typedef __bf16 bf16x4 __attribute__((ext_vector_type(4)));
typedef float  f32x4  __attribute__((ext_vector_type(4)));

#define QPL ((size_t)TT*1024)
#define KPL ((size_t)TT*256)
#define VPL ((size_t)8*64*TS)
#define APL ((size_t)TT*1024)
#define H1PL ((size_t)TT*1024)

__device__ __forceinline__ f32x4 mfma16(bf16x8 a, bf16x8 b, f32x4 c){
  return __builtin_amdgcn_mfma_f32_16x16x32_bf16(a, b, c, 0, 0, 0);
}
__device__ __forceinline__ void gload_lds16(const void* g, void* lds){
  __builtin_amdgcn_global_load_lds(
      (const __attribute__((address_space(1))) unsigned int*)g,
      (__attribute__((address_space(3))) unsigned int*)lds, 16, 0, 0);
}
__device__ __forceinline__ void split3f(float x, bf16& h, bf16& m, bf16& l){
  h = (bf16)x; float r = x - (float)h;
  m = (bf16)r; r -= (float)m;
  l = (bf16)r;
}

// ---------------- transpose + f32->bf16 (1-way, MoE weights) ----------------
__global__ __launch_bounds__(256) void tcvt_k(const float* __restrict__ src, bf16* __restrict__ dst,
                                              int R, int C, long srcMatStride, long dstMatStride, long dstOff){
  __shared__ float tile[32][33];
  int z = blockIdx.z;
  const float* s = src + (size_t)z*srcMatStride;
  bf16* d = dst + (size_t)z*dstMatStride + dstOff;
  int r0 = blockIdx.y*32, c0 = blockIdx.x*32;
  int tx = threadIdx.x, ty = threadIdx.y;
  #pragma unroll
  for (int i=0;i<4;i++)
    tile[ty+i*8][tx] = s[(size_t)(r0+ty+i*8)*C + c0+tx];
  __syncthreads();
  #pragma unroll
  for (int i=0;i<4;i++)
    d[(size_t)(c0+ty+i*8)*R + r0+tx] = (bf16)tile[tx][ty+i*8];
}

// ---------------- transpose + 3-way split (precise weights) ----------------
__global__ __launch_bounds__(256) void tcvt3_k(const float* __restrict__ src, bf16* __restrict__ dst,
                                               int R, int C, long planeStride, long dstOff){
  __shared__ float tile[32][33];
  int r0 = blockIdx.y*32, c0 = blockIdx.x*32;
  int tx = threadIdx.x, ty = threadIdx.y;
  #pragma unroll
  for (int i=0;i<4;i++)
    tile[ty+i*8][tx] = src[(size_t)(r0+ty+i*8)*C + c0+tx];
  __syncthreads();
  #pragma unroll
  for (int i=0;i<4;i++){
    float v = tile[tx][ty+i*8];
    bf16 h,m,l; split3f(v,h,m,l);
    size_t o = dstOff + (size_t)(c0+ty+i*8)*R + r0+tx;
    dst[o] = h; dst[planeStride + o] = m; dst[2*planeStride + o] = l;
  }
}

// ---------------- RMSNorm f32 -> bf16 (1-way, for MoE h2) ----------------
__global__ __launch_bounds__(256) void rmsnorm_k(const float* __restrict__ x, const float* __restrict__ g,
                                                 bf16* __restrict__ o){
  int row = blockIdx.x, tid = threadIdx.x, wid = tid>>6, lane = tid&63;
  f32x4 v = ((const f32x4*)(x + (size_t)row*1024))[tid];
  float ss = v[0]*v[0]+v[1]*v[1]+v[2]*v[2]+v[3]*v[3];
  #pragma unroll
  for (int m=1;m<64;m<<=1) ss += __shfl_xor(ss, m);
  __shared__ float red[4];
  if (lane==0) red[wid] = ss;
  __syncthreads();
  float tot = red[0]+red[1]+red[2]+red[3];
  float inv = rsqrtf(tot*(1.f/1024.f) + 1e-6f);
  f32x4 gv = ((const f32x4*)g)[tid];
  bf16x4 ov;
  #pragma unroll
  for (int i=0;i<4;i++) ov[i] = (bf16)(v[i]*inv*gv[i]);
  *(bf16x4*)(o + (size_t)row*1024 + tid*4) = ov;
}

// ---------------- RMSNorm f32 -> 3-way split bf16 planes ----------------
__global__ __launch_bounds__(256) void rmsnorm3_k(const float* __restrict__ x, const float* __restrict__ g,
                                                  bf16* __restrict__ o3){
  int row = blockIdx.x, tid = threadIdx.x, wid = tid>>6, lane = tid&63;
  f32x4 v = ((const f32x4*)(x + (size_t)row*1024))[tid];
  float ss = v[0]*v[0]+v[1]*v[1]+v[2]*v[2]+v[3]*v[3];
  #pragma unroll
  for (int m=1;m<64;m<<=1) ss += __shfl_xor(ss, m);
  __shared__ float red[4];
  if (lane==0) red[wid] = ss;
  __syncthreads();
  float tot = red[0]+red[1]+red[2]+red[3];
  float inv = rsqrtf(tot*(1.f/1024.f) + 1e-6f);
  f32x4 gv = ((const f32x4*)g)[tid];
  #pragma unroll
  for (int i=0;i<4;i++){
    float val = v[i]*inv*gv[i];
    bf16 h,m,l; split3f(val,h,m,l);
    size_t idx = (size_t)row*1024 + tid*4 + i;
    o3[idx] = h; o3[H1PL + idx] = m; o3[2*H1PL + idx] = l;
  }
}

// ---------------- plain bf16 GEMM (MoE path) ----------------
template<int OUT_BF16, int RESID, int GATHER, int GROUPED>
__global__ __launch_bounds__(256) void gemm_k(
    const bf16* __restrict__ Aptr, int lda,
    const bf16* __restrict__ Bt, long bMatStride,
    void* __restrict__ Cout, int ldc,
    const float* __restrict__ resid,
    const int* __restrict__ gidx,
    const int* __restrict__ grpBase,
    const int* __restrict__ grpCnt,
    int M, int K){
  int tid = threadIdx.x;
  int wid = tid >> 6, lane = tid & 63;
  int lr = lane & 15, lg = lane >> 4;
  int e = blockIdx.z;
  int base = GROUPED ? grpBase[e] : 0;
  int cnt  = GROUPED ? grpCnt[e]  : M;
  int m0 = blockIdx.y * 128;
  if (m0 >= cnt) return;
  int bn0 = blockIdx.x * 128;
  const bf16* Bte = Bt + (size_t)e * bMatStride;

  __shared__ __align__(16) bf16 As[128*32];
  __shared__ __align__(16) bf16 Bs[128*32];

  int rA0 = tid >> 2, colA = (tid & 3) * 8;
  long arow[2], brow[2];
  #pragma unroll
  for (int i=0;i<2;i++){
    int r = rA0 + i*64;
    int ar = m0 + r; if (ar > cnt-1) ar = cnt-1;
    arow[i] = GATHER ? (long)gidx[base + ar] : (long)(base + ar);
    brow[i] = bn0 + r;
  }

  f32x4 zero4 = {0.f,0.f,0.f,0.f};
  f32x4 acc[4][4];
  #pragma unroll
  for (int m=0;m<4;m++)
    #pragma unroll
    for (int n=0;n<4;n++) acc[m][n] = zero4;

  char* ldsA = (char*)As + wid*1024;
  char* ldsB = (char*)Bs + wid*1024;
  int wr = (wid>>1)*64, wc = (wid&1)*64;

  for (int k0 = 0; k0 < K; k0 += 32){
    #pragma unroll
    for (int i=0;i<2;i++){
      gload_lds16(Aptr + arow[i]*lda + k0 + colA, ldsA + i*4096);
      gload_lds16(Bte  + brow[i]*K   + k0 + colA, ldsB + i*4096);
    }
    asm volatile("s_waitcnt vmcnt(0)" ::: "memory");
    __syncthreads();
    bf16x8 af[4], bfr[4];
    #pragma unroll
    for (int m=0;m<4;m++) af[m]  = *(const bf16x8*)&As[(wr + m*16 + lr)*32 + lg*8];
    #pragma unroll
    for (int n=0;n<4;n++) bfr[n] = *(const bf16x8*)&Bs[(wc + n*16 + lr)*32 + lg*8];
    #pragma unroll
    for (int m=0;m<4;m++)
      #pragma unroll
      for (int n=0;n<4;n++)
        acc[m][n] = mfma16(af[m], bfr[n], acc[m][n]);
    __syncthreads();
  }
  #pragma unroll
  for (int m=0;m<4;m++){
    #pragma unroll
    for (int j=0;j<4;j++){
      int gr = m0 + wr + m*16 + lg*4 + j;
      if (gr < cnt){
        size_t orow = (size_t)(base + gr);
        #pragma unroll
        for (int n=0;n<4;n++){
          int gc = bn0 + wc + n*16 + lr;
          float v = acc[m][n][j];
          if (OUT_BF16){
            ((bf16*)Cout)[orow*ldc + gc] = (bf16)v;
          } else {
            float rv = RESID ? resid[orow*ldc + gc] : 0.f;
            ((float*)Cout)[orow*ldc + gc] = v + rv;
          }
        }
      }
    }
  }
}

// ---------------- split-3 precise GEMM: C f32 = A3 * B3^T (+resid) ----------------
template<int RESID>
__global__ __launch_bounds__(256) void gemm3_k(
    const bf16* __restrict__ A3, long aPL, int lda,
    const bf16* __restrict__ B3, long bPL, int K,
    float* __restrict__ C, int ldc,
    const float* __restrict__ resid){
  int tid = threadIdx.x;
  int wid = tid >> 6, lane = tid & 63;
  int lr = lane & 15, lg = lane >> 4;
  int m0 = blockIdx.y * 128, bn0 = blockIdx.x * 128;

  __shared__ __align__(16) bf16 As[3*128*32];
  __shared__ __align__(16) bf16 Bs[3*128*32];

  int rA0 = tid >> 2, colA = (tid & 3) * 8;
  f32x4 zero4 = {0.f,0.f,0.f,0.f};
  f32x4 acc[4][4];
  #pragma unroll
  for (int m=0;m<4;m++)
    #pragma unroll
    for (int n=0;n<4;n++) acc[m][n] = zero4;

  int wr = (wid>>1)*64, wc = (wid&1)*64;

  for (int k0 = 0; k0 < K; k0 += 32){
    #pragma unroll
    for (int p=0;p<3;p++){
      #pragma unroll
      for (int i=0;i<2;i++){
        int r = rA0 + i*64;
        gload_lds16(A3 + (size_t)p*aPL + (size_t)(m0 + r)*lda + k0 + colA,
                    (char*)As + p*8192 + wid*1024 + i*4096);
        gload_lds16(B3 + (size_t)p*bPL + (size_t)(bn0 + r)*K + k0 + colA,
                    (char*)Bs + p*8192 + wid*1024 + i*4096);
      }
    }
    asm volatile("s_waitcnt vmcnt(0)" ::: "memory");
    __syncthreads();
    bf16x8 af[3][4], bfr[3][4];
    #pragma unroll
    for (int p=0;p<3;p++){
      #pragma unroll
      for (int m=0;m<4;m++) af[p][m]  = *(const bf16x8*)&As[p*4096 + (wr + m*16 + lr)*32 + lg*8];
      #pragma unroll
      for (int n=0;n<4;n++) bfr[p][n] = *(const bf16x8*)&Bs[p*4096 + (wc + n*16 + lr)*32 + lg*8];
    }
    #pragma unroll
    for (int m=0;m<4;m++)
      #pragma unroll
      for (int n=0;n<4;n++){
        f32x4 a = acc[m][n];
        a = mfma16(af[0][m], bfr[0][n], a);   // hh
        a = mfma16(af[0][m], bfr[1][n], a);   // hm
        a = mfma16(af[1][m], bfr[0][n], a);   // mh
        a = mfma16(af[0][m], bfr[2][n], a);   // hl
        a = mfma16(af[1][m], bfr[1][n], a);   // mm
        a = mfma16(af[2][m], bfr[0][n], a);   // lh
        acc[m][n] = a;
      }
    __syncthreads();
  }
  #pragma unroll
  for (int m=0;m<4;m++){
    #pragma unroll
    for (int j=0;j<4;j++){
      size_t orow = (size_t)(m0 + wr + m*16 + lg*4 + j);
      #pragma unroll
      for (int n=0;n<4;n++){
        int gc = bn0 + wc + n*16 + lr;
        float v = acc[m][n][j];
        if (RESID) v += resid[orow*ldc + gc];
        C[orow*ldc + gc] = v;
      }
    }
  }
}

// ---------------- per-head QK RMSNorm + RoPE (f32) -> 3-way split q/k ----------------
__global__ __launch_bounds__(256) void rope3_k(const float* __restrict__ qkv, bf16* __restrict__ Q3,
                                               bf16* __restrict__ K3, const int* __restrict__ idxp,
                                               const float* __restrict__ qg, const float* __restrict__ kg){
  int tid = threadIdx.x, wid = tid>>6, lane = tid&63;
  int u = blockIdx.x*4 + wid;   // 0 .. TT*20-1
  int t = u / 20, r = u % 20;
  bool isq = (r < 16);
  int srcOff = isq ? r*64 : 1024 + (r-16)*64;
  float val = qkv[(size_t)t*1536 + srcOff + lane];
  float ss = val*val;
  #pragma unroll
  for (int m=1;m<64;m<<=1) ss += __shfl_xor(ss, m);
  float inv = rsqrtf(ss*(1.f/64.f) + 1e-6f);
  const float* gm = isq ? qg : kg;
  val = val * inv * gm[lane];
  bool rope = ((idxp[0] + 1) % 4) != 0;
  if (rope){
    int s = t & (TS-1);
    float fi = (float)(lane & ~1);
    float theta = (float)exp((double)fi * -0.14391156831212787);
    float ang = (float)s * theta;
    float sn, cs;
    sincosf(ang, &sn, &cs);
    float other = __shfl_xor(val, 1);
    val = (lane & 1) ? (other*sn + val*cs) : (val*cs - other*sn);
  }
  bf16 h,m2,l; split3f(val,h,m2,l);
  if (isq){
    size_t base = (size_t)t*1024 + r*64 + lane;
    Q3[base] = h; Q3[QPL + base] = m2; Q3[2*QPL + base] = l;
  } else {
    size_t base = (size_t)t*256 + (r-16)*64 + lane;
    K3[base] = h; K3[KPL + base] = m2; K3[2*KPL + base] = l;
  }
}

// ---------------- V transpose f32 -> 3-way split bf16 [b4+kvh][64][S] ----------------
__global__ __launch_bounds__(256) void vtrans3_k(const float* __restrict__ src, bf16* __restrict__ dst){
  __shared__ float tile[32][33];
  int z = blockIdx.z;  // b*4 + kvh
  const float* s = src + (size_t)(z>>2)*((size_t)TS*1536) + (z&3)*64 + 1280;
  int r0 = blockIdx.y*32, c0 = blockIdx.x*32;
  int tx = threadIdx.x, ty = threadIdx.y;
  #pragma unroll
  for (int i=0;i<4;i++)
    tile[ty+i*8][tx] = s[(size_t)(r0+ty+i*8)*1536 + c0+tx];
  __syncthreads();
  size_t zb = (size_t)z*(64*TS);
  #pragma unroll
  for (int i=0;i<4;i++){
    float v = tile[tx][ty+i*8];
    bf16 h,m,l; split3f(v,h,m,l);
    size_t o = zb + (size_t)(c0+ty+i*8)*TS + r0+tx;
    dst[o] = h; dst[VPL + o] = m; dst[2*VPL + o] = l;
  }
}

// ---------------- precise chunked-causal GQA flash attention (split MFMA) ----------------
// KV tile = 32 tokens. LDS 32KB -> 4 blocks/CU. K tile XOR-swizzled (both sides):
// store: lane fetches global colblock cb=(l&7)^((l>>3)&7), LDS write stays linear;
// read: col index ^= (row&7)<<3. V (64B rows) and Ps (64B rows) are 2-way (free).
__global__ __launch_bounds__(256) void attn3_k(const bf16* __restrict__ Q3, const bf16* __restrict__ K3,
                                               const bf16* __restrict__ V3, bf16* __restrict__ A3,
                                               const int* __restrict__ idxp){
  int tid = threadIdx.x, wid = tid>>6, lane = tid&63;
  int lr = lane&15, lg = lane>>4;
  int qt = blockIdx.x, h = blockIdx.y, b = blockIdx.z;
  int kvh = h >> 2;
  int q0 = qt*64;
  bool rope = ((idxp[0]+1) % 4) != 0;
  int kstart = rope ? (q0 / TCHUNK) * TCHUNK : 0;
  int ntiles = (q0 + 64 - kstart) >> 5;

  __shared__ __align__(16) bf16 Ks[3*32*64];   // [plane][token(32)][d(64)] swizzled
  __shared__ __align__(16) bf16 Vs[3*64*32];   // [plane][d(64)][token(32)] linear
  __shared__ __align__(16) bf16 Ps[4][2][16*32];

  // Q fragments in registers
  bf16x8 qf[3][2];
  {
    size_t qrow = (size_t)(b*TS + q0 + wid*16 + lr);
    #pragma unroll
    for (int p=0;p<3;p++)
      #pragma unroll
      for (int kf=0;kf<2;kf++)
        qf[p][kf] = *(const bf16x8*)&Q3[(size_t)p*QPL + qrow*1024 + h*64 + kf*32 + lg*8];
  }

  // staging indices
  int krow = tid>>3;                       // 0..31 (token within tile)
  int kcb  = (tid&7) ^ (krow&7);           // pre-swizzled colblock (d)
  int vrow = tid>>2;                       // 0..63 (d)
  int vcb  = tid&3;                        // token colblock

  f32x4 o[4];
  f32x4 zero4 = {0.f,0.f,0.f,0.f};
  #pragma unroll
  for (int n=0;n<4;n++) o[n] = zero4;
  float mrow[4], lrow[4];
  #pragma unroll
  for (int j=0;j<4;j++){ mrow[j] = -1e30f; lrow[j] = 0.f; }

  for (int kt=0; kt<ntiles; kt++){
    int kt0 = kstart + kt*32;
    #pragma unroll
    for (int p=0;p<3;p++){
      gload_lds16(K3 + (size_t)p*KPL + ((size_t)(b*TS + kt0 + krow))*256 + kvh*64 + kcb*8,
                  (char*)Ks + p*4096 + wid*1024);
      gload_lds16(V3 + (size_t)p*VPL + ((size_t)((b*4 + kvh)*64 + vrow))*TS + kt0 + vcb*8,
                  (char*)Vs + p*4096 + wid*1024);
    }
    asm volatile("s_waitcnt vmcnt(0)" ::: "memory");
    __syncthreads();

    // QK^T: 3x3 limbs, 6 products, cf in {0,1}
    f32x4 sc[2];
    #pragma unroll
    for (int cf=0; cf<2; cf++){
      int r = cf*16 + lr;
      int sw = (lr&7) << 3;
      bf16x8 kh0 = *(const bf16x8*)&Ks[0*2048 + r*64 + (((lg  )<<3) ^ sw)];
      bf16x8 kh1 = *(const bf16x8*)&Ks[0*2048 + r*64 + (((lg+4)<<3) ^ sw)];
      bf16x8 km0 = *(const bf16x8*)&Ks[1*2048 + r*64 + (((lg  )<<3) ^ sw)];
      bf16x8 km1 = *(const bf16x8*)&Ks[1*2048 + r*64 + (((lg+4)<<3) ^ sw)];
      bf16x8 kl0 = *(const bf16x8*)&Ks[2*2048 + r*64 + (((lg  )<<3) ^ sw)];
      bf16x8 kl1 = *(const bf16x8*)&Ks[2*2048 + r*64 + (((lg+4)<<3) ^ sw)];
      f32x4 a = zero4;
      a = mfma16(qf[0][0], kh0, a); a = mfma16(qf[0][1], kh1, a);  // hh
      a = mfma16(qf[0][0], km0, a); a = mfma16(qf[0][1], km1, a);  // hm
      a = mfma16(qf[1][0], kh0, a); a = mfma16(qf[1][1], kh1, a);  // mh
      a = mfma16(qf[0][0], kl0, a); a = mfma16(qf[0][1], kl1, a);  // hl
      a = mfma16(qf[1][0], km0, a); a = mfma16(qf[1][1], km1, a);  // mm
      a = mfma16(qf[2][0], kh0, a); a = mfma16(qf[2][1], kh1, a);  // lh
      sc[cf] = a;
    }
    // online softmax (f32), write P split 2-way
    #pragma unroll
    for (int j=0;j<4;j++){
      int qtok = q0 + wid*16 + lg*4 + j;
      float pmax = -1e30f;
      #pragma unroll
      for (int cf=0;cf<2;cf++){
        int ktok = kt0 + cf*16 + lr;
        float sv = (ktok <= qtok) ? sc[cf][j]*0.125f : -1e30f;
        sc[cf][j] = sv;
        pmax = fmaxf(pmax, sv);
      }
      #pragma unroll
      for (int m=1;m<16;m<<=1) pmax = fmaxf(pmax, __shfl_xor(pmax, m));
      float mnew = fmaxf(mrow[j], pmax);
      float corr = __expf(mrow[j]-mnew);
      float psum = 0.f;
      #pragma unroll
      for (int cf=0;cf<2;cf++){
        float p = __expf(sc[cf][j]-mnew);
        sc[cf][j] = p;
        psum += p;
      }
      #pragma unroll
      for (int m=1;m<16;m<<=1) psum += __shfl_xor(psum, m);
      lrow[j] = lrow[j]*corr + psum;
      mrow[j] = mnew;
      #pragma unroll
      for (int n=0;n<4;n++) o[n][j] *= corr;
      #pragma unroll
      for (int cf=0;cf<2;cf++){
        float p = sc[cf][j];
        bf16 ph = (bf16)p;
        bf16 pl = (bf16)(p - (float)ph);
        int pidx = (lg*4+j)*32 + cf*16 + lr;
        Ps[wid][0][pidx] = ph;
        Ps[wid][1][pidx] = pl;
      }
    }
    __syncthreads();
    // PV: P 2-limb x V 3-limb, 5 products; K-dim = 32 (one frag)
    bf16x8 pa0 = *(const bf16x8*)&Ps[wid][0][lr*32 + lg*8];
    bf16x8 pa1 = *(const bf16x8*)&Ps[wid][1][lr*32 + lg*8];
    #pragma unroll
    for (int n=0;n<4;n++){
      bf16x8 vh = *(const bf16x8*)&Vs[0*2048 + (n*16+lr)*32 + lg*8];
      bf16x8 vm = *(const bf16x8*)&Vs[1*2048 + (n*16+lr)*32 + lg*8];
      bf16x8 vl = *(const bf16x8*)&Vs[2*2048 + (n*16+lr)*32 + lg*8];
      f32x4 a = o[n];
      a = mfma16(pa0, vh, a);   // hh
      a = mfma16(pa0, vm, a);   // hm
      a = mfma16(pa1, vh, a);   // lh
      a = mfma16(pa0, vl, a);   // hl
      a = mfma16(pa1, vm, a);   // lm
      o[n] = a;
    }
    __syncthreads();
  }
  // epilogue: normalize + 3-way split store for the precise w_o GEMM
  #pragma unroll
  for (int j=0;j<4;j++){
    int qtok = q0 + wid*16 + lg*4 + j;
    float invl = 1.f / lrow[j];
    size_t rowb = ((size_t)(b*TS + qtok))*1024 + h*64;
    #pragma unroll
    for (int n=0;n<4;n++){
      float v = o[n][j]*invl;
      bf16 h2,m2,l2; split3f(v,h2,m2,l2);
      size_t oidx = rowb + n*16 + lr;
      A3[oidx] = h2; A3[APL + oidx] = m2; A3[2*APL + oidx] = l2;
    }
  }
}

// ---------------- fused f32 router ----------------
__global__ __launch_bounds__(256) void router_k(const float* __restrict__ x2, const float* __restrict__ g2,
                                                const float* __restrict__ wr,
                                                int* __restrict__ topi, float* __restrict__ topw){
  int tid = threadIdx.x, wid = tid>>6, lane = tid&63;
  int t = blockIdx.x*4 + wid;
  const float* row = x2 + (size_t)t*1024;
  f32x4 xv[4];
  float ss = 0.f;
  #pragma unroll
  for (int j=0;j<4;j++){
    xv[j] = ((const f32x4*)row)[lane + j*64];
    ss += xv[j][0]*xv[j][0]+xv[j][1]*xv[j][1]+xv[j][2]*xv[j][2]+xv[j][3]*xv[j][3];
  }
  #pragma unroll
  for (int m=1;m<64;m<<=1) ss += __shfl_xor(ss, m);
  float inv = 1.f / sqrtf(ss*(1.f/1024.f) + 1e-6f);
  float a[8] = {0,0,0,0,0,0,0,0};
  #pragma unroll
  for (int j=0;j<4;j++){
    #pragma unroll
    for (int c=0;c<4;c++){
      int d = (lane + j*64)*4 + c;
      float hv = xv[j][c]*inv*g2[d];
      f32x4 wa = ((const f32x4*)(wr + (size_t)d*8))[0];
      f32x4 wb = ((const f32x4*)(wr + (size_t)d*8))[1];
      a[0]+=hv*wa[0]; a[1]+=hv*wa[1]; a[2]+=hv*wa[2]; a[3]+=hv*wa[3];
      a[4]+=hv*wb[0]; a[5]+=hv*wb[1]; a[6]+=hv*wb[2]; a[7]+=hv*wb[3];
    }
  }
  #pragma unroll
  for (int e2=0;e2<8;e2++)
    #pragma unroll
    for (int m=1;m<64;m<<=1) a[e2] += __shfl_xor(a[e2], m);
  if (lane==0){
    int i0=0; float l0=a[0];
    #pragma unroll
    for (int e2=1;e2<8;e2++) if (a[e2] > l0){ l0=a[e2]; i0=e2; }
    int i1=-1; float l1=-1e30f;
    #pragma unroll
    for (int e2=0;e2<8;e2++){ if (e2==i0) continue; if (a[e2] > l1){ l1=a[e2]; i1=e2; } }
    float w0 = 1.f/(1.f + __expf(l1 - l0));
    topi[t*2]=i0; topi[t*2+1]=i1;
    topw[t*2]=w0; topw[t*2+1]=1.f-w0;
  }
}

__global__ void count_k(const int* __restrict__ topi, int* __restrict__ cnt){
  int i = blockIdx.x*256 + threadIdx.x;
  if (i < TT*2) atomicAdd(&cnt[topi[i]], 1);
}
__global__ void scan_k(const int* __restrict__ cnt, int* __restrict__ basep){
  if (threadIdx.x==0){ int run=0; for (int e=0;e<8;e++){ basep[e]=run; run+=cnt[e]; } }
}
__global__ void scatter_k(const int* __restrict__ topi, const int* __restrict__ basep,
                          int* __restrict__ cursor, int* __restrict__ rowsb, int* __restrict__ t2p){
  int i = blockIdx.x*256 + threadIdx.x;
  if (i < TT*2){
    int e = topi[i];
    int p = basep[e] + atomicAdd(&cursor[e], 1);
    rowsb[p] = i>>1;
    t2p[i] = p;
  }
}

__global__ void silumul_k(const bf16* __restrict__ raw, bf16* __restrict__ o, int rows){
  int i = blockIdx.x*256 + threadIdx.x;
  int pos = i >> 7, f = (i & 127)*8;
  if (pos >= rows) return;
  bf16x8 g = *(const bf16x8*)&raw[(size_t)pos*2048 + f];
  bf16x8 u = *(const bf16x8*)&raw[(size_t)pos*2048 + 1024 + f];
  bf16x8 r;
  #pragma unroll
  for (int k=0;k<8;k++){
    float gf = (float)g[k], uf = (float)u[k];
    r[k] = (bf16)(gf * uf / (1.f + __expf(-gf)));
  }
  *(bf16x8*)&o[(size_t)pos*1024 + f] = r;
}

__global__ void combine_k(const float* __restrict__ acc, const bf16* __restrict__ eo,
                          const float* __restrict__ topw, const int* __restrict__ t2p,
                          float* __restrict__ out){
  int i = blockIdx.x*256 + threadIdx.x;
  int t = i >> 8, c = (i & 255)*4;
  int p0 = t2p[t*2], p1 = t2p[t*2+1];
  float w0 = topw[t*2], w1 = topw[t*2+1];
  f32x4 a = *(const f32x4*)&acc[(size_t)t*1024 + c];
  bf16x4 e0 = *(const bf16x4*)&eo[(size_t)p0*1024 + c];
  bf16x4 e1 = *(const bf16x4*)&eo[(size_t)p1*1024 + c];
  f32x4 r;
  #pragma unroll
  for (int k=0;k<4;k++) r[k] = a[k] + w0*(float)e0[k] + w1*(float)e1[k];
  *(f32x4*)&out[(size_t)t*1024 + c] = r;
}

extern "C" void kernel_launch(void* const* d_in, const int* in_sizes, int n_in,
                              void* d_out, int out_size, void* d_ws, size_t ws_size,
                              hipStream_t stream){
  const float* x        = (const float*)d_in[0];
  const int*   idx      = (const int*)d_in[1];
  const float* gamma1   = (const float*)d_in[2];
  const float* gamma2   = (const float*)d_in[3];
  const float* qg       = (const float*)d_in[4];
  const float* kg       = (const float*)d_in[5];
  const float* w_q      = (const float*)d_in[6];
  const float* w_k      = (const float*)d_in[7];
  const float* w_v      = (const float*)d_in[8];
  const float* w_o      = (const float*)d_in[9];
  const float* w_router = (const float*)d_in[10];
  const float* sh_wg    = (const float*)d_in[11];
  const float* sh_wu    = (const float*)d_in[12];
  const float* sh_wd    = (const float*)d_in[13];
  const float* e_wg     = (const float*)d_in[14];
  const float* e_wu     = (const float*)d_in[15];
  const float* e_wd     = (const float*)d_in[16];
  float* out = (float*)d_out;

  char* ws = (char*)d_ws;
  size_t off = 0;
  auto alloc = [&](size_t n)->char*{ char* p = ws + off; off += (n + 255) & ~(size_t)255; return p; };

  const long PLQKV = (long)1536*1024;
  const long PLSQ  = (long)1024*1024;

  bf16* wqkv3  = (bf16*)alloc((size_t)3*1536*1024*2);
  bf16* wo3    = (bf16*)alloc((size_t)3*1024*1024*2);
  bf16* shwgu_t= (bf16*)alloc((size_t)2048*1024*2);
  bf16* shwd_t = (bf16*)alloc((size_t)1024*1024*2);
  bf16* ewgu_t = (bf16*)alloc((size_t)8*2048*1024*2);
  bf16* ewd_t  = (bf16*)alloc((size_t)8*1024*1024*2);
  bf16* h1s    = (bf16*)alloc((size_t)3*TT*1024*2);
  float* qkvraw= (float*)alloc((size_t)TT*1536*4);
  bf16* q3     = (bf16*)alloc((size_t)3*TT*1024*2);
  bf16* k3     = (bf16*)alloc((size_t)3*TT*256*2);
  bf16* v3     = (bf16*)alloc((size_t)3*8*64*TS*2);
  float* x2    = (float*)alloc((size_t)TT*1024*4);
  float* accb  = (float*)alloc((size_t)TT*1024*4);
  char* BUF1   = alloc((size_t)8192*2048*2);
  char* BUF2   = alloc((size_t)8192*1024*2);
  bf16* eo     = (bf16*)alloc((size_t)8192*1024*2);
  int*   topi  = (int*)alloc((size_t)TT*2*4);
  float* topw  = (float*)alloc((size_t)TT*2*4);
  int*   rowsb = (int*)alloc((size_t)TT*2*4);
  int*   t2p   = (int*)alloc((size_t)TT*2*4);
  int*   cntp  = (int*)alloc(256);
  int*   basep = (int*)alloc(256);
  int*   curp  = (int*)alloc(256);
  (void)ws_size; (void)in_sizes; (void)n_in; (void)out_size;

  bf16* a3     = (bf16*)qkvraw;
  bf16* h2     = q3;
  bf16* shraw  = (bf16*)BUF1;
  bf16* guraw  = (bf16*)BUF1;
  bf16* shg    = (bf16*)BUF2;
  bf16* gu     = (bf16*)BUF2;

  dim3 tb(32,8);
  tcvt3_k<<<dim3(32,32,1), tb, 0, stream>>>(w_q, wqkv3, 1024,1024, PLQKV, 0);
  tcvt3_k<<<dim3(8,32,1),  tb, 0, stream>>>(w_k, wqkv3, 1024,256,  PLQKV, (long)1024*1024);
  tcvt3_k<<<dim3(8,32,1),  tb, 0, stream>>>(w_v, wqkv3, 1024,256,  PLQKV, (long)1280*1024);
  tcvt3_k<<<dim3(32,32,1), tb, 0, stream>>>(w_o, wo3,   1024,1024, PLSQ, 0);
  tcvt_k<<<dim3(32,32,1), tb, 0, stream>>>(sh_wg, shwgu_t, 1024,1024, 0,0, 0);
  tcvt_k<<<dim3(32,32,1), tb, 0, stream>>>(sh_wu, shwgu_t, 1024,1024, 0,0, (long)1024*1024);
  tcvt_k<<<dim3(32,32,1), tb, 0, stream>>>(sh_wd, shwd_t, 1024,1024, 0,0, 0);
  tcvt_k<<<dim3(32,32,8), tb, 0, stream>>>(e_wg, ewgu_t, 1024,1024, (long)1024*1024, (long)2048*1024, 0);
  tcvt_k<<<dim3(32,32,8), tb, 0, stream>>>(e_wu, ewgu_t, 1024,1024, (long)1024*1024, (long)2048*1024, (long)1024*1024);
  tcvt_k<<<dim3(32,32,8), tb, 0, stream>>>(e_wd, ewd_t,  1024,1024, (long)1024*1024, (long)1024*1024, 0);

  rmsnorm3_k<<<TT, 256, 0, stream>>>(x, gamma1, h1s);
  gemm3_k<0><<<dim3(12,32,1), 256, 0, stream>>>(h1s, (long)H1PL, 1024, wqkv3, PLQKV, 1024,
                                                qkvraw, 1536, nullptr);
  rope3_k<<<TT*20/4, 256, 0, stream>>>(qkvraw, q3, k3, idx, qg, kg);
  vtrans3_k<<<dim3(2,64,8), tb, 0, stream>>>(qkvraw, v3);
  attn3_k<<<dim3(32,16,2), 256, 0, stream>>>(q3, k3, v3, a3, idx);
  gemm3_k<1><<<dim3(8,32,1), 256, 0, stream>>>(a3, (long)APL, 1024, wo3, PLSQ, 1024,
                                               x2, 1024, x);
  rmsnorm_k<<<TT, 256, 0, stream>>>(x2, gamma2, h2);
  router_k<<<TT/4, 256, 0, stream>>>(x2, gamma2, w_router, topi, topw);
  hipMemsetAsync(cntp, 0, 3*256, stream);
  count_k<<<32, 256, 0, stream>>>(topi, cntp);
  scan_k<<<1, 64, 0, stream>>>(cntp, basep);
  scatter_k<<<32, 256, 0, stream>>>(topi, basep, curp, rowsb, t2p);
  gemm_k<1,0,0,0><<<dim3(16,32,1), 256, 0, stream>>>(h2,1024, shwgu_t,0, shraw,2048,
                                                     nullptr, nullptr, nullptr, nullptr, TT, 1024);
  silumul_k<<<(TT*128)/256, 256, 0, stream>>>(shraw, shg, TT);
  gemm_k<0,1,0,0><<<dim3(8,32,1), 256, 0, stream>>>(shg,1024, shwd_t,0, accb,1024,
                                                    x2, nullptr, nullptr, nullptr, TT, 1024);
  gemm_k<1,0,1,1><<<dim3(16,64,8), 256, 0, stream>>>(h2,1024, ewgu_t,(long)2048*1024, guraw,2048,
                                                     nullptr, rowsb, basep, cntp, TT, 1024);
  silumul_k<<<(2*TT*128)/256, 256, 0, stream>>>(guraw, gu, 2*TT);
  gemm_k<1,0,0,1><<<dim3(8,64,8), 256, 0, stream>>>(gu,1024, ewd_t,(long)1024*1024, eo,1024,
                                                    nullptr, nullptr, basep, cntp, TT, 1024);
  combine_k<<<TT, 256, 0, stream>>>(accb, eo, topw, t2p, out);
}